// Round 11
// baseline (1836.772 us; speedup 1.0000x reference)
//
#include <hip/hip_runtime.h>
#include <math.h>

#define VOCAB 1000
#define EMB   128
#define HID   256
#define G4    1024   // 4*HID
#define BATCH 64
#define SEQT  1024
#define NT    512    // threads: 8 waves, 2 waves/SIMD -> 256 unified regs/wave
#define KVC   23     // register chunks (4 half2 cols each): cols 0..91
#define KLC   9      // LDS tail chunks: cols 92..127

typedef unsigned int u32;
typedef _Float16 f16;
typedef __attribute__((ext_vector_type(2))) _Float16 h2v;
union H2U { u32 u; h2v h; unsigned short s[2]; };

#if defined(__has_builtin)
# if __has_builtin(__builtin_amdgcn_fdot2)
#  define HAVE_FDOT2 1
# endif
#endif
__device__ __forceinline__ float fdot2_(u32 a, u32 b, float c) {
    H2U ua, ub; ua.u = a; ub.u = b;
#ifdef HAVE_FDOT2
    return __builtin_amdgcn_fdot2(ua.h, ub.h, c, false);   // v_dot2_f32_f16
#else
    return c + (float)ua.h.x * (float)ub.h.x + (float)ua.h.y * (float)ub.h.y;
#endif
}

__device__ __forceinline__ float sigmoidf_(float x) {
    return 1.f / (1.f + __expf(-x));
}
__device__ __forceinline__ float tanhf_(float x) {
    return 1.f - 2.f / (__expf(2.f * x) + 1.f);
}

// thread tau -> its two gate rows. Lane-pair mapping: wave w lane l=2m+e
// owns unit u=32w+m; e=0 -> rows (i_u, g_u), e=1 -> rows (f_u, o_u).
__device__ __forceinline__ void rows_of(int tau, int& rA, int& rB, int& u, int& e) {
    const int w = tau >> 6, l = tau & 63;
    e = l & 1;
    u = (w << 5) + (l >> 1);
    rA = e ? (HID + u) : u;            // f : i
    rB = e ? (3 * HID + u) : (2 * HID + u);   // o : g
}

// ---------------------------------------------------------------------------
// Kernel 1: eproj[v][g] = emb[v] . W_ih[g] + b_ih[g] + b_hh[g]   (fp32, exact)
// ---------------------------------------------------------------------------
__global__ __launch_bounds__(1024) void eproj_kernel(
    const float* __restrict__ emb, const float* __restrict__ W_ih,
    const float* __restrict__ b_ih, const float* __restrict__ b_hh,
    float* __restrict__ eproj)
{
    const int v = blockIdx.x;
    const int g = threadIdx.x;
    __shared__ __align__(16) float x_sh[EMB];
    if (g < EMB / 4) {
        ((float4*)x_sh)[g] = ((const float4*)(emb + (size_t)v * EMB))[g];
    }
    __syncthreads();
    const float4* wrow = (const float4*)(W_ih + (size_t)g * EMB);
    float a0 = 0.f, a1 = 0.f, a2 = 0.f, a3 = 0.f;
#pragma unroll
    for (int e4 = 0; e4 < EMB / 4; e4++) {
        float4 wv = wrow[e4];
        float4 xv = ((const float4*)x_sh)[e4];
        a0 += wv.x * xv.x;
        a1 += wv.y * xv.y;
        a2 += wv.z * xv.z;
        a3 += wv.w * xv.w;
    }
    eproj[(size_t)v * G4 + g] = (a0 + a1) + (a2 + a3) + b_ih[g] + b_hh[g];
}

// ---------------------------------------------------------------------------
// Kernel 2: pack W_hh fp32 -> fp16 half2 uint4 chunks keyed by CONSUMING
// thread: wvq[(q*2+slot)*NT + tau] = rows rA/rB(tau), half2 cols 4q..4q+3.
// Same for wlq (tail chunks). Consecutive tau -> consecutive 16B: both the
// one-time global loads and the per-step LDS b128 reads are conflict-free.
// ---------------------------------------------------------------------------
__global__ __launch_bounds__(NT) void pack_whh(
    const float* __restrict__ Whh, uint4* __restrict__ wvq, uint4* __restrict__ wlq)
{
    const int c   = blockIdx.x;          // chunk 0..(KVC+KLC-1)
    const int tau = threadIdx.x;
    int rA, rB, u, e;
    rows_of(tau, rA, rB, u, e);
    const int rows[2] = { rA, rB };
#pragma unroll
    for (int slot = 0; slot < 2; slot++) {
        const int r = rows[slot];
        const int mbase = 4 * c;         // half2 col base (tail handled below)
        const int mc = (c < KVC) ? mbase : (4 * KVC + 4 * (c - KVC));
        H2U q0, q1, q2, q3;
        q0.h.x = (f16)Whh[(size_t)r * HID + 2 * (mc + 0)];
        q0.h.y = (f16)Whh[(size_t)r * HID + 2 * (mc + 0) + 1];
        q1.h.x = (f16)Whh[(size_t)r * HID + 2 * (mc + 1)];
        q1.h.y = (f16)Whh[(size_t)r * HID + 2 * (mc + 1) + 1];
        q2.h.x = (f16)Whh[(size_t)r * HID + 2 * (mc + 2)];
        q2.h.y = (f16)Whh[(size_t)r * HID + 2 * (mc + 2) + 1];
        q3.h.x = (f16)Whh[(size_t)r * HID + 2 * (mc + 3)];
        q3.h.y = (f16)Whh[(size_t)r * HID + 2 * (mc + 3) + 1];
        uint4 pk = { q0.u, q1.u, q2.u, q3.u };
        if (c < KVC) wvq[((size_t)c * 2 + slot) * NT + tau] = pk;
        else         wlq[((size_t)(c - KVC) * 2 + slot) * NT + tau] = pk;
    }
}

// ---------------------------------------------------------------------------
// Kernel 3: single-CU LSTM, ONE barrier per step.
// 512 threads (2 waves/SIMD -> hard 256-reg unified cap, AGPR-backed weights,
// no scratch -- the R10-verified allocation). Lane-pair mapping puts all four
// gates of unit u on adjacent lanes of ONE wave: the f,o partial sums reach
// the unit owner via __shfl_xor(.,1) -- no LDS bounce, no second barrier.
// Parity-double-buffered h makes the single end-of-step barrier sufficient.
// ---------------------------------------------------------------------------
__global__ __launch_bounds__(NT, 2) void lstm_single_cu(
    const int* __restrict__ ids, const int* __restrict__ lens,
    const float* __restrict__ eproj,
    const uint4* __restrict__ wvq, const uint4* __restrict__ wlq,
    float* __restrict__ out)
{
    const int b   = blockIdx.x;
    const int tau = threadIdx.x;
    int rA, rB, u, e;
    rows_of(tau, rA, rB, u, e);

    __shared__ uint4 wl_sh[KLC * 2 * NT];        // 144 KB weight tail
    __shared__ u32   h2_sh[2][HID / 2];          // h as half2, parity x2

    // stage LDS weight tail (b128 both sides, coalesced; 18 uint4/thread)
#pragma unroll
    for (int t = 0; t < (KLC * 2 * NT) / NT; t++)
        wl_sh[t * NT + tau] = wlq[t * NT + tau];
    if (tau < HID / 2) h2_sh[0][tau] = 0u;       // h(0) = 0

    // persistent weights: 2 rows x 92 half2 = 184 regs (AGPR-backed)
    u32 wA[KVC * 4], wB[KVC * 4];
#pragma unroll
    for (int q = 0; q < KVC; q++) {
        uint4 ta = wvq[(q * 2 + 0) * NT + tau];
        uint4 tb = wvq[(q * 2 + 1) * NT + tau];
        wA[4 * q + 0] = ta.x; wA[4 * q + 1] = ta.y;
        wA[4 * q + 2] = ta.z; wA[4 * q + 3] = ta.w;
        wB[4 * q + 0] = tb.x; wB[4 * q + 1] = tb.y;
        wB[4 * q + 2] = tb.z; wB[4 * q + 3] = tb.w;
    }

    const int len = lens[b];                     // >= 1
    const int* idr = ids + (size_t)b * SEQT;
    float c = 0.f, hf = 0.f;

    const float* e0 = eproj + (size_t)idr[0] * G4;
    float xA = e0[rA], xB = e0[rB];

    __syncthreads();

    for (int t = 0; t < len; t++) {
        // prefetch next step's input projections (hidden under dot loops)
        const int nt = (t + 1 < len) ? t + 1 : len - 1;
        const float* en = eproj + (size_t)idr[nt] * G4;
        const float nA = en[rA], nB = en[rB];

        const int p = t & 1;
        const uint4* hb4 = (const uint4*)h2_sh[p];   // 32 b128 broadcasts
        float aA = xA, aB = xB;

        // ---- register chunks, software-pipelined h prefetch ----
        uint4 hc = hb4[0];
#pragma unroll
        for (int q = 0; q < KVC; q++) {
            const uint4 hn = hb4[q + 1];             // next chunk's h (q=22 -> tail h)
            aA = fdot2_(wA[4 * q + 0], hc.x, aA);
            aB = fdot2_(wB[4 * q + 0], hc.x, aB);
            aA = fdot2_(wA[4 * q + 1], hc.y, aA);
            aB = fdot2_(wB[4 * q + 1], hc.y, aB);
            aA = fdot2_(wA[4 * q + 2], hc.z, aA);
            aB = fdot2_(wB[4 * q + 2], hc.z, aB);
            aA = fdot2_(wA[4 * q + 3], hc.w, aA);
            aB = fdot2_(wB[4 * q + 3], hc.w, aB);
            hc = hn;
        }
        // ---- LDS tail chunks, pipelined weight+h prefetch ----
        uint4 tA = wl_sh[0 * NT + tau];
        uint4 tB = wl_sh[1 * NT + tau];
#pragma unroll
        for (int q = 0; q < KLC; q++) {
            uint4 tAn, tBn, hn;
            if (q + 1 < KLC) {
                tAn = wl_sh[((q + 1) * 2 + 0) * NT + tau];
                tBn = wl_sh[((q + 1) * 2 + 1) * NT + tau];
                hn  = hb4[KVC + q + 1];
            }
            aA = fdot2_(tA.x, hc.x, aA);
            aB = fdot2_(tB.x, hc.x, aB);
            aA = fdot2_(tA.y, hc.y, aA);
            aB = fdot2_(tB.y, hc.y, aB);
            aA = fdot2_(tA.z, hc.z, aA);
            aB = fdot2_(tB.z, hc.z, aB);
            aA = fdot2_(tA.w, hc.w, aA);
            aB = fdot2_(tB.w, hc.w, aB);
            if (q + 1 < KLC) { tA = tAn; tB = tBn; hc = hn; }
        }

        // ---- in-wave gate exchange: partner lane has (f,o) / (i,g) ----
        const float pA = __shfl_xor(aA, 1);   // even lane: f_sum ; odd: i_sum
        const float pB = __shfl_xor(aB, 1);   // even lane: o_sum ; odd: g_sum

        if (e == 0) {                // unit owner (even lane): full activation
            float ig = sigmoidf_(aA);
            float gg = tanhf_(aB);
            float fg = sigmoidf_(pA);
            float og = sigmoidf_(pB);
            c = fg * c + ig * gg;
            hf = og * tanhf_(c);
            H2U hv; hv.h.x = (f16)hf; hv.h.y = (f16)0.f;
            ((unsigned short*)h2_sh[p ^ 1])[u] = hv.s[0];
        }
        xA = nA; xB = nB;
        __syncthreads();             // the ONE barrier per step
    }

    if (e == 0) out[(size_t)b * HID + u] = hf;
}

// ---------------------------------------------------------------------------
// Fallback (ws too small): correct-but-slow single-block fp32 version.
// ---------------------------------------------------------------------------
__global__ __launch_bounds__(1024, 1) void lstm_fallback(
    const int* __restrict__ ids, const int* __restrict__ lens,
    const float* __restrict__ emb, const float* __restrict__ W_ih,
    const float* __restrict__ b_ih, const float* __restrict__ b_hh,
    const float* __restrict__ W_hh, float* __restrict__ out)
{
    const int b = blockIdx.x;
    const int t = threadIdx.x;

    __shared__ __align__(16) float h_sh[HID];
    __shared__ __align__(16) float c_sh[HID];
    __shared__ __align__(16) float gates[G4];
    __shared__ __align__(16) float x_sh[EMB];

    float wih[EMB];
    {
        const float4* wr = (const float4*)(W_ih + (size_t)t * EMB);
#pragma unroll
        for (int e4 = 0; e4 < EMB / 4; e4++) {
            float4 wv = wr[e4];
            wih[4 * e4 + 0] = wv.x;
            wih[4 * e4 + 1] = wv.y;
            wih[4 * e4 + 2] = wv.z;
            wih[4 * e4 + 3] = wv.w;
        }
    }
    float bias = b_ih[t] + b_hh[t];

    const int len = lens[b];
    const int* ids_row = ids + (size_t)b * SEQT;
    if (t < HID) { h_sh[t] = 0.f; c_sh[t] = 0.f; }
    __syncthreads();

    for (int step = 0; step < len; step++) {
        int id = ids_row[step];
        if (t < EMB / 4) {
            ((float4*)x_sh)[t] = ((const float4*)(emb + (size_t)id * EMB))[t];
        }
        __syncthreads();
        float a0 = bias, a1 = 0.f, a2 = 0.f, a3 = 0.f;
#pragma unroll
        for (int e4 = 0; e4 < EMB / 4; e4++) {
            float4 xv = ((const float4*)x_sh)[e4];
            a0 += wih[4 * e4 + 0] * xv.x;
            a1 += wih[4 * e4 + 1] * xv.y;
            a2 += wih[4 * e4 + 2] * xv.z;
            a3 += wih[4 * e4 + 3] * xv.w;
        }
        float acc = (a0 + a1) + (a2 + a3);

        const float* wrow = W_hh + (size_t)t * HID;
        a0 = acc; a1 = 0.f; a2 = 0.f; a3 = 0.f;
        for (int k4 = 0; k4 < HID / 4; k4++) {
            float4 hv = ((const float4*)h_sh)[k4];
            float4 wv = ((const float4*)wrow)[k4];
            a0 += wv.x * hv.x;
            a1 += wv.y * hv.y;
            a2 += wv.z * hv.z;
            a3 += wv.w * hv.w;
        }
        gates[t] = (a0 + a1) + (a2 + a3);
        __syncthreads();

        if (t < HID) {
            float ig = sigmoidf_(gates[t]);
            float fg = sigmoidf_(gates[HID + t]);
            float gg = tanhf_(gates[2 * HID + t]);
            float og = sigmoidf_(gates[3 * HID + t]);
            float cc = fg * c_sh[t] + ig * gg;
            c_sh[t] = cc;
            h_sh[t] = og * tanhf_(cc);
        }
        __syncthreads();
    }
    if (t < HID) out[(size_t)b * HID + t] = h_sh[t];
}

extern "C" void kernel_launch(void* const* d_in, const int* in_sizes, int n_in,
                              void* d_out, int out_size, void* d_ws, size_t ws_size,
                              hipStream_t stream) {
    const int*   ids  = (const int*)d_in[0];
    const int*   lens = (const int*)d_in[1];
    const float* emb  = (const float*)d_in[2];
    const float* Wih  = (const float*)d_in[3];
    const float* Whh  = (const float*)d_in[4];
    const float* bih  = (const float*)d_in[5];
    const float* bhh  = (const float*)d_in[6];
    float* out = (float*)d_out;

    // ws layout: eproj 4 MB | wvq 368 KB | wlq 144 KB
    const size_t ep_bytes = (size_t)VOCAB * G4 * sizeof(float);
    const size_t wv_off   = ep_bytes;
    const size_t wv_bytes = (size_t)KVC * 2 * NT * sizeof(uint4);
    const size_t wl_off   = wv_off + wv_bytes;
    const size_t wl_bytes = (size_t)KLC * 2 * NT * sizeof(uint4);

    if (ws_size >= wl_off + wl_bytes) {
        float* eproj = (float*)d_ws;
        uint4* wvp   = (uint4*)((char*)d_ws + wv_off);
        uint4* wlp   = (uint4*)((char*)d_ws + wl_off);
        eproj_kernel<<<VOCAB, 1024, 0, stream>>>(emb, Wih, bih, bhh, eproj);
        pack_whh<<<KVC + KLC, NT, 0, stream>>>(Whh, wvp, wlp);
        lstm_single_cu<<<BATCH, NT, 0, stream>>>(ids, lens, eproj, wvp, wlp, out);
    } else {
        lstm_fallback<<<BATCH, 1024, 0, stream>>>(
            ids, lens, emb, Wih, bih, bhh, Whh, out);
    }
}